// Round 5
// baseline (261.843 us; speedup 1.0000x reference)
//
#include <hip/hip_runtime.h>

#define INV_SQRT_2F 0.70710678118654752440f

typedef float fvec4 __attribute__((ext_vector_type(4)));

// fp32 -> bf16 bits, round-to-nearest-even (inputs are normal floats here).
static __device__ __forceinline__ unsigned short f2bf(float f)
{
    unsigned int u = __float_as_uint(f);
    u += 0x7fffu + ((u >> 16) & 1u);
    return (unsigned short)(u >> 16);
}

// Expand two uint4 (8 bf16 each) from src/dst streams, combine, NT-store 8 fp32.
static __device__ __forceinline__ void combine8(uint4 a, uint4 b, fvec4* dstp)
{
    fvec4 r0, r1;
    r0.x = (__uint_as_float(a.x << 16)         + __uint_as_float(b.x << 16))         * INV_SQRT_2F;
    r0.y = (__uint_as_float(a.x & 0xffff0000u) + __uint_as_float(b.x & 0xffff0000u)) * INV_SQRT_2F;
    r0.z = (__uint_as_float(a.y << 16)         + __uint_as_float(b.y << 16))         * INV_SQRT_2F;
    r0.w = (__uint_as_float(a.y & 0xffff0000u) + __uint_as_float(b.y & 0xffff0000u)) * INV_SQRT_2F;
    r1.x = (__uint_as_float(a.z << 16)         + __uint_as_float(b.z << 16))         * INV_SQRT_2F;
    r1.y = (__uint_as_float(a.z & 0xffff0000u) + __uint_as_float(b.z & 0xffff0000u)) * INV_SQRT_2F;
    r1.z = (__uint_as_float(a.w << 16)         + __uint_as_float(b.w << 16))         * INV_SQRT_2F;
    r1.w = (__uint_as_float(a.w & 0xffff0000u) + __uint_as_float(b.w & 0xffff0000u)) * INV_SQRT_2F;
    __builtin_nontemporal_store(r0, dstp);
    __builtin_nontemporal_store(r1, dstp + 1);
}

// ---------------------------------------------------------------------------
// Kernel 1: per-node channel mix.  y[b,n,o,v] = sum_i W[o,i] * x[b,n,i,v]
// One block per (b,node). Threads 0..63 -> W_src rows, 64..127 -> W_dst rows.
// y stored as bf16, batch-interleaved per node: row = [b0: 192][b1: 192]
// (768 B contiguous per node per array).
// ---------------------------------------------------------------------------
__global__ void __launch_bounds__(128)
node_transform(const float* __restrict__ x,
               const float* __restrict__ W_src,
               const float* __restrict__ W_dst,
               unsigned short* __restrict__ y_src,
               unsigned short* __restrict__ y_dst,
               int nodes, int bn_total)
{
    __shared__ float xs[192];
    int bn = blockIdx.x;               // bn = b*nodes + n  (x is [b][n][192])
    if (bn >= bn_total) return;
    int b = bn / nodes;
    int n = bn - b * nodes;

    const float4* xp = (const float4*)(x + (size_t)bn * 192);
    int t = threadIdx.x;
    if (t < 48) ((float4*)xs)[t] = xp[t];   // 192 floats = 48 float4
    __syncthreads();

    int o = t & 63;
    const float*    W = (t < 64) ? W_src : W_dst;
    unsigned short* y = (t < 64) ? y_src : y_dst;

    const float4* Wrow = (const float4*)(W + o * 64);
    float a0 = 0.f, a1 = 0.f, a2 = 0.f;
#pragma unroll
    for (int i4 = 0; i4 < 16; ++i4) {
        float4 w = Wrow[i4];
        int i = i4 * 4;
        a0 = fmaf(w.x, xs[(i + 0) * 3 + 0], a0);
        a1 = fmaf(w.x, xs[(i + 0) * 3 + 1], a1);
        a2 = fmaf(w.x, xs[(i + 0) * 3 + 2], a2);
        a0 = fmaf(w.y, xs[(i + 1) * 3 + 0], a0);
        a1 = fmaf(w.y, xs[(i + 1) * 3 + 1], a1);
        a2 = fmaf(w.y, xs[(i + 1) * 3 + 2], a2);
        a0 = fmaf(w.z, xs[(i + 2) * 3 + 0], a0);
        a1 = fmaf(w.z, xs[(i + 2) * 3 + 1], a1);
        a2 = fmaf(w.z, xs[(i + 2) * 3 + 2], a2);
        a0 = fmaf(w.w, xs[(i + 3) * 3 + 0], a0);
        a1 = fmaf(w.w, xs[(i + 3) * 3 + 1], a1);
        a2 = fmaf(w.w, xs[(i + 3) * 3 + 2], a2);
    }
    // batch-interleaved bf16: row = n*2 + b, 192 elems per (node,batch)
    unsigned short* yp = y + ((size_t)n * 2 + b) * 192 + o * 3;
    yp[0] = f2bf(a0);
    yp[1] = f2bf(a1);
    yp[2] = f2bf(a2);
}

// ---------------------------------------------------------------------------
// Kernel 2: edge gather (bf16, 16 B/lane) + add + scale -> fp32 NT stores.
// 24 threads per edge (j in [0,24)); each thread covers 8 channels x 2 batches:
// 4x uint4 gathers (64 B), 4x float4 stores (64 B). Block 192 = 8 edges, no
// grid-stride loop, no per-iteration division.
// ---------------------------------------------------------------------------
__global__ void __launch_bounds__(192)
edge_combine(const unsigned short* __restrict__ y_src,
             const unsigned short* __restrict__ y_dst,
             const int* __restrict__ src,
             const int* __restrict__ dst,
             float* __restrict__ out,
             int edges)
{
    const uint4* ys = (const uint4*)y_src;       // node row = 48 uint4 (2 batches)
    const uint4* yd = (const uint4*)y_dst;
    fvec4*       o4 = (fvec4*)out;

    int le = threadIdx.x / 24;                   // local edge 0..7
    int j  = threadIdx.x - le * 24;              // quad index 0..23
    int e  = blockIdx.x * 8 + le;
    if (e >= edges) return;

    size_t sb = (size_t)src[e] * 48 + j;
    size_t db = (size_t)dst[e] * 48 + j;

    uint4 a0 = ys[sb];
    uint4 b0 = yd[db];
    uint4 a1 = ys[sb + 24];
    uint4 b1 = yd[db + 24];

    combine8(a0, b0, &o4[(size_t)e * 48 + 2 * j]);
    combine8(a1, b1, &o4[((size_t)edges + e) * 48 + 2 * j]);
}

// ---------------------------------------------------------------------------
// Fallback (only if ws_size is too small): fused per-edge matmul, fp32.
// ---------------------------------------------------------------------------
__global__ void __launch_bounds__(64)
edge_fused(const float* __restrict__ x,
           const float* __restrict__ W_src,
           const float* __restrict__ W_dst,
           const int* __restrict__ src,
           const int* __restrict__ dst,
           float* __restrict__ out,
           int edges, int nodes)
{
    __shared__ float xs[192];
    __shared__ float xd[192];
    int be = blockIdx.x;
    int b  = be / edges;
    int e  = be - b * edges;
    int s  = src[e];
    int d  = dst[e];
    const float* xps = x + ((size_t)b * nodes + s) * 192;
    const float* xpd = x + ((size_t)b * nodes + d) * 192;
    int t = threadIdx.x;
#pragma unroll
    for (int k = 0; k < 3; ++k) {
        xs[t + 64 * k] = xps[t + 64 * k];
        xd[t + 64 * k] = xpd[t + 64 * k];
    }
    __syncthreads();
    float a0 = 0.f, a1 = 0.f, a2 = 0.f;
#pragma unroll
    for (int i = 0; i < 64; ++i) {
        float ws = W_src[t * 64 + i];
        float wd = W_dst[t * 64 + i];
        a0 += ws * xs[i * 3 + 0] + wd * xd[i * 3 + 0];
        a1 += ws * xs[i * 3 + 1] + wd * xd[i * 3 + 1];
        a2 += ws * xs[i * 3 + 2] + wd * xd[i * 3 + 2];
    }
    float* op = out + ((size_t)b * edges + e) * 192 + t * 3;
    op[0] = a0 * INV_SQRT_2F;
    op[1] = a1 * INV_SQRT_2F;
    op[2] = a2 * INV_SQRT_2F;
}

extern "C" void kernel_launch(void* const* d_in, const int* in_sizes, int n_in,
                              void* d_out, int out_size, void* d_ws, size_t ws_size,
                              hipStream_t stream)
{
    const float* x     = (const float*)d_in[0];
    const float* W_src = (const float*)d_in[1];
    const float* W_dst = (const float*)d_in[2];
    const int*   src   = (const int*)d_in[3];
    const int*   dst   = (const int*)d_in[4];
    float*       out   = (float*)d_out;

    const int batch = 2;
    const int edges = in_sizes[3];
    const int nodes = in_sizes[0] / (batch * 192);   // 192 = dim_in * 3

    const size_t y_elems = (size_t)batch * nodes * 192;        // per array
    const size_t needed  = 2 * y_elems * sizeof(unsigned short);

    if (ws_size >= needed) {
        unsigned short* y_src = (unsigned short*)d_ws;
        unsigned short* y_dst = y_src + y_elems;
        const int bn_total = batch * nodes;
        node_transform<<<bn_total, 128, 0, stream>>>(x, W_src, W_dst,
                                                     y_src, y_dst, nodes, bn_total);
        const int eb = (edges + 7) / 8;
        edge_combine<<<eb, 192, 0, stream>>>(y_src, y_dst, src, dst, out, edges);
    } else {
        edge_fused<<<batch * edges, 64, 0, stream>>>(x, W_src, W_dst,
                                                     src, dst, out, edges, nodes);
    }
}

// Round 6
// 241.040 us; speedup vs baseline: 1.0863x; 1.0863x over previous
//
#include <hip/hip_runtime.h>

#define INV_SQRT_2F 0.70710678118654752440f

typedef float fvec4 __attribute__((ext_vector_type(4)));

// fp32 -> bf16 bits, round-to-nearest-even (inputs are normal floats here).
static __device__ __forceinline__ unsigned short f2bf(float f)
{
    unsigned int u = __float_as_uint(f);
    u += 0x7fffu + ((u >> 16) & 1u);
    return (unsigned short)(u >> 16);
}

// ---------------------------------------------------------------------------
// Sort-prep kernels: counting sort of edges by src node.
// ---------------------------------------------------------------------------
__global__ void zero_u32(unsigned int* __restrict__ p, int n)
{
    int i = blockIdx.x * blockDim.x + threadIdx.x;
    if (i < n) p[i] = 0u;
}

__global__ void hist_src(const int* __restrict__ src,
                         unsigned int* __restrict__ cnt, int edges)
{
    int i = blockIdx.x * blockDim.x + threadIdx.x;
    int stride = gridDim.x * blockDim.x;
    for (; i < edges; i += stride) atomicAdd(&cnt[src[i]], 1u);
}

// Single-block exclusive scan over nodes counters -> cursor.
__global__ void __launch_bounds__(1024)
scan_offsets(const unsigned int* __restrict__ cnt,
             unsigned int* __restrict__ cursor, int n)
{
    __shared__ unsigned int part[1024];
    int t = threadIdx.x;
    int per = (n + 1023) / 1024;
    int lo = t * per;
    int hi = lo + per; if (hi > n) hi = n;
    unsigned int s = 0;
    for (int i = lo; i < hi; ++i) s += cnt[i];
    part[t] = s;
    __syncthreads();
    for (int d = 1; d < 1024; d <<= 1) {
        unsigned int v = (t >= d) ? part[t - d] : 0u;
        __syncthreads();
        part[t] += v;
        __syncthreads();
    }
    unsigned int base = (t > 0) ? part[t - 1] : 0u;
    for (int i = lo; i < hi; ++i) {
        unsigned int c = cnt[i];
        cursor[i] = base;
        base += c;
    }
}

// Scatter edges into src-sorted order; sde[pos] = (src<<16 | dst, orig_e).
__global__ void scatter_edges(const int* __restrict__ src,
                              const int* __restrict__ dst,
                              unsigned int* __restrict__ cursor,
                              uint2* __restrict__ sde, int edges)
{
    int i = blockIdx.x * blockDim.x + threadIdx.x;
    int stride = gridDim.x * blockDim.x;
    for (; i < edges; i += stride) {
        unsigned int s = (unsigned int)src[i];
        unsigned int d = (unsigned int)dst[i];
        unsigned int pos = atomicAdd(&cursor[s], 1u);
        sde[pos] = make_uint2((s << 16) | d, (unsigned int)i);
    }
}

// ---------------------------------------------------------------------------
// Kernel 1: per-node channel mix.  y[b,n,o,v] = sum_i W[o,i] * x[b,n,i,v]
// One block per (b,node). Threads 0..63 -> W_src rows, 64..127 -> W_dst rows.
// y stored as bf16, batch-interleaved per node (768 B contiguous per node).
// ---------------------------------------------------------------------------
__global__ void __launch_bounds__(128)
node_transform(const float* __restrict__ x,
               const float* __restrict__ W_src,
               const float* __restrict__ W_dst,
               unsigned short* __restrict__ y_src,
               unsigned short* __restrict__ y_dst,
               int nodes, int bn_total)
{
    __shared__ float xs[192];
    int bn = blockIdx.x;               // bn = b*nodes + n  (x is [b][n][192])
    if (bn >= bn_total) return;
    int b = bn / nodes;
    int n = bn - b * nodes;

    const float4* xp = (const float4*)(x + (size_t)bn * 192);
    int t = threadIdx.x;
    if (t < 48) ((float4*)xs)[t] = xp[t];   // 192 floats = 48 float4
    __syncthreads();

    int o = t & 63;
    const float*    W = (t < 64) ? W_src : W_dst;
    unsigned short* y = (t < 64) ? y_src : y_dst;

    const float4* Wrow = (const float4*)(W + o * 64);
    float a0 = 0.f, a1 = 0.f, a2 = 0.f;
#pragma unroll
    for (int i4 = 0; i4 < 16; ++i4) {
        float4 w = Wrow[i4];
        int i = i4 * 4;
        a0 = fmaf(w.x, xs[(i + 0) * 3 + 0], a0);
        a1 = fmaf(w.x, xs[(i + 0) * 3 + 1], a1);
        a2 = fmaf(w.x, xs[(i + 0) * 3 + 2], a2);
        a0 = fmaf(w.y, xs[(i + 1) * 3 + 0], a0);
        a1 = fmaf(w.y, xs[(i + 1) * 3 + 1], a1);
        a2 = fmaf(w.y, xs[(i + 1) * 3 + 2], a2);
        a0 = fmaf(w.z, xs[(i + 2) * 3 + 0], a0);
        a1 = fmaf(w.z, xs[(i + 2) * 3 + 1], a1);
        a2 = fmaf(w.z, xs[(i + 2) * 3 + 2], a2);
        a0 = fmaf(w.w, xs[(i + 3) * 3 + 0], a0);
        a1 = fmaf(w.w, xs[(i + 3) * 3 + 1], a1);
        a2 = fmaf(w.w, xs[(i + 3) * 3 + 2], a2);
    }
    unsigned short* yp = y + ((size_t)n * 2 + b) * 192 + o * 3;
    yp[0] = f2bf(a0);
    yp[1] = f2bf(a1);
    yp[2] = f2bf(a2);
}

// ---------------------------------------------------------------------------
// Kernel 2 (src-sorted): edge gather (bf16) + add + scale -> fp32 NT stores.
// R4's proven lane mapping: item = (pe, j), j in [0,48): one uint2 (4 bf16)
// per array per batch, one contiguous float4 store per batch. Edges iterated
// in src-sorted order so consecutive items hit the same y_src row (cache-hot).
// ---------------------------------------------------------------------------
__global__ void __launch_bounds__(256)
edge_combine_sorted(const unsigned short* __restrict__ y_src,
                    const unsigned short* __restrict__ y_dst,
                    const uint2* __restrict__ sde,
                    float* __restrict__ out,
                    int edges)
{
    const int total  = edges * 48;
    const int stride = gridDim.x * blockDim.x;
    const uint2* ys = (const uint2*)y_src;
    const uint2* yd = (const uint2*)y_dst;
    fvec4*       o4 = (fvec4*)out;

    for (int t = blockIdx.x * blockDim.x + threadIdx.x; t < total; t += stride) {
        int pe = t / 48;
        int j  = t - pe * 48;
        uint2 se = sde[pe];
        unsigned int s = se.x >> 16;
        unsigned int d = se.x & 0xffffu;
        unsigned int e = se.y;

        size_t sb = (size_t)s * 96 + j;      // 96 uint2 per node (2 batches)
        size_t db = (size_t)d * 96 + j;

        uint2 a0 = ys[sb];
        uint2 b0 = yd[db];
        uint2 a1 = ys[sb + 48];
        uint2 b1 = yd[db + 48];

        fvec4 r0, r1;
        r0.x = (__uint_as_float(a0.x << 16)         + __uint_as_float(b0.x << 16))         * INV_SQRT_2F;
        r0.y = (__uint_as_float(a0.x & 0xffff0000u) + __uint_as_float(b0.x & 0xffff0000u)) * INV_SQRT_2F;
        r0.z = (__uint_as_float(a0.y << 16)         + __uint_as_float(b0.y << 16))         * INV_SQRT_2F;
        r0.w = (__uint_as_float(a0.y & 0xffff0000u) + __uint_as_float(b0.y & 0xffff0000u)) * INV_SQRT_2F;
        r1.x = (__uint_as_float(a1.x << 16)         + __uint_as_float(b1.x << 16))         * INV_SQRT_2F;
        r1.y = (__uint_as_float(a1.x & 0xffff0000u) + __uint_as_float(b1.x & 0xffff0000u)) * INV_SQRT_2F;
        r1.z = (__uint_as_float(a1.y << 16)         + __uint_as_float(b1.y << 16))         * INV_SQRT_2F;
        r1.w = (__uint_as_float(a1.y & 0xffff0000u) + __uint_as_float(b1.y & 0xffff0000u)) * INV_SQRT_2F;

        __builtin_nontemporal_store(r0, &o4[(size_t)e * 48 + j]);
        __builtin_nontemporal_store(r1, &o4[((size_t)edges + e) * 48 + j]);
    }
}

// ---------------------------------------------------------------------------
// Unsorted variant (fallback when nodes don't fit 16-bit packing): R4 kernel.
// ---------------------------------------------------------------------------
__global__ void __launch_bounds__(256)
edge_combine(const unsigned short* __restrict__ y_src,
             const unsigned short* __restrict__ y_dst,
             const int* __restrict__ src,
             const int* __restrict__ dst,
             float* __restrict__ out,
             int edges)
{
    const int total  = edges * 48;
    const int stride = gridDim.x * blockDim.x;
    const uint2* ys = (const uint2*)y_src;
    const uint2* yd = (const uint2*)y_dst;
    fvec4*       o4 = (fvec4*)out;

    for (int t = blockIdx.x * blockDim.x + threadIdx.x; t < total; t += stride) {
        int e = t / 48;
        int j = t - e * 48;
        size_t sb = (size_t)src[e] * 96 + j;
        size_t db = (size_t)dst[e] * 96 + j;

        uint2 a0 = ys[sb];
        uint2 b0 = yd[db];
        uint2 a1 = ys[sb + 48];
        uint2 b1 = yd[db + 48];

        fvec4 r0, r1;
        r0.x = (__uint_as_float(a0.x << 16)         + __uint_as_float(b0.x << 16))         * INV_SQRT_2F;
        r0.y = (__uint_as_float(a0.x & 0xffff0000u) + __uint_as_float(b0.x & 0xffff0000u)) * INV_SQRT_2F;
        r0.z = (__uint_as_float(a0.y << 16)         + __uint_as_float(b0.y << 16))         * INV_SQRT_2F;
        r0.w = (__uint_as_float(a0.y & 0xffff0000u) + __uint_as_float(b0.y & 0xffff0000u)) * INV_SQRT_2F;
        r1.x = (__uint_as_float(a1.x << 16)         + __uint_as_float(b1.x << 16))         * INV_SQRT_2F;
        r1.y = (__uint_as_float(a1.x & 0xffff0000u) + __uint_as_float(b1.x & 0xffff0000u)) * INV_SQRT_2F;
        r1.z = (__uint_as_float(a1.y << 16)         + __uint_as_float(b1.y << 16))         * INV_SQRT_2F;
        r1.w = (__uint_as_float(a1.y & 0xffff0000u) + __uint_as_float(b1.y & 0xffff0000u)) * INV_SQRT_2F;

        __builtin_nontemporal_store(r0, &o4[(size_t)e * 48 + j]);
        __builtin_nontemporal_store(r1, &o4[((size_t)edges + e) * 48 + j]);
    }
}

// ---------------------------------------------------------------------------
// Fallback (ws too small): fused per-edge matmul, fp32.
// ---------------------------------------------------------------------------
__global__ void __launch_bounds__(64)
edge_fused(const float* __restrict__ x,
           const float* __restrict__ W_src,
           const float* __restrict__ W_dst,
           const int* __restrict__ src,
           const int* __restrict__ dst,
           float* __restrict__ out,
           int edges, int nodes)
{
    __shared__ float xs[192];
    __shared__ float xd[192];
    int be = blockIdx.x;
    int b  = be / edges;
    int e  = be - b * edges;
    int s  = src[e];
    int d  = dst[e];
    const float* xps = x + ((size_t)b * nodes + s) * 192;
    const float* xpd = x + ((size_t)b * nodes + d) * 192;
    int t = threadIdx.x;
#pragma unroll
    for (int k = 0; k < 3; ++k) {
        xs[t + 64 * k] = xps[t + 64 * k];
        xd[t + 64 * k] = xpd[t + 64 * k];
    }
    __syncthreads();
    float a0 = 0.f, a1 = 0.f, a2 = 0.f;
#pragma unroll
    for (int i = 0; i < 64; ++i) {
        float ws = W_src[t * 64 + i];
        float wd = W_dst[t * 64 + i];
        a0 += ws * xs[i * 3 + 0] + wd * xd[i * 3 + 0];
        a1 += ws * xs[i * 3 + 1] + wd * xd[i * 3 + 1];
        a2 += ws * xs[i * 3 + 2] + wd * xd[i * 3 + 2];
    }
    float* op = out + ((size_t)b * edges + e) * 192 + t * 3;
    op[0] = a0 * INV_SQRT_2F;
    op[1] = a1 * INV_SQRT_2F;
    op[2] = a2 * INV_SQRT_2F;
}

extern "C" void kernel_launch(void* const* d_in, const int* in_sizes, int n_in,
                              void* d_out, int out_size, void* d_ws, size_t ws_size,
                              hipStream_t stream)
{
    const float* x     = (const float*)d_in[0];
    const float* W_src = (const float*)d_in[1];
    const float* W_dst = (const float*)d_in[2];
    const int*   src   = (const int*)d_in[3];
    const int*   dst   = (const int*)d_in[4];
    float*       out   = (float*)d_out;

    const int batch = 2;
    const int edges = in_sizes[3];
    const int nodes = in_sizes[0] / (batch * 192);   // 192 = dim_in * 3

    const size_t y_elems = (size_t)batch * nodes * 192;          // per array
    const size_t y_bytes = ((y_elems * 2 + 255) / 256) * 256;    // bf16, aligned
    const size_t cnt_bytes = (((size_t)nodes * 4 + 255) / 256) * 256;
    const size_t sde_bytes = ((size_t)edges * 8 + 255) / 256 * 256;
    const size_t needed_sorted = 2 * y_bytes + 2 * cnt_bytes + sde_bytes;
    const size_t needed_plain  = 2 * y_bytes;

    char* wsb = (char*)d_ws;

    if (ws_size >= needed_sorted && nodes <= 65535) {
        unsigned short* y_src  = (unsigned short*)wsb;
        unsigned short* y_dst  = (unsigned short*)(wsb + y_bytes);
        unsigned int*   cnt    = (unsigned int*)(wsb + 2 * y_bytes);
        unsigned int*   cursor = (unsigned int*)(wsb + 2 * y_bytes + cnt_bytes);
        uint2*          sde    = (uint2*)(wsb + 2 * y_bytes + 2 * cnt_bytes);

        const int bn_total = batch * nodes;
        node_transform<<<bn_total, 128, 0, stream>>>(x, W_src, W_dst,
                                                     y_src, y_dst, nodes, bn_total);
        zero_u32<<<(nodes + 255) / 256, 256, 0, stream>>>(cnt, nodes);
        int egrid = (edges + 255) / 256; if (egrid > 2048) egrid = 2048;
        hist_src<<<egrid, 256, 0, stream>>>(src, cnt, edges);
        scan_offsets<<<1, 1024, 0, stream>>>(cnt, cursor, nodes);
        scatter_edges<<<egrid, 256, 0, stream>>>(src, dst, cursor, sde, edges);
        edge_combine_sorted<<<2048, 256, 0, stream>>>(y_src, y_dst, sde, out, edges);
    } else if (ws_size >= needed_plain) {
        unsigned short* y_src = (unsigned short*)wsb;
        unsigned short* y_dst = (unsigned short*)(wsb + y_bytes);
        const int bn_total = batch * nodes;
        node_transform<<<bn_total, 128, 0, stream>>>(x, W_src, W_dst,
                                                     y_src, y_dst, nodes, bn_total);
        edge_combine<<<2048, 256, 0, stream>>>(y_src, y_dst, src, dst, out, edges);
    } else {
        edge_fused<<<batch * edges, 64, 0, stream>>>(x, W_src, W_dst,
                                                     src, dst, out, edges, nodes);
    }
}

// Round 7
// 211.338 us; speedup vs baseline: 1.2390x; 1.1405x over previous
//
#include <hip/hip_runtime.h>

#define INV_SQRT_2F 0.70710678118654752440f

typedef float fvec4 __attribute__((ext_vector_type(4)));

// fp32 -> bf16 bits, round-to-nearest-even (inputs are normal floats here).
static __device__ __forceinline__ unsigned short f2bf(float f)
{
    unsigned int u = __float_as_uint(f);
    u += 0x7fffu + ((u >> 16) & 1u);
    return (unsigned short)(u >> 16);
}

// Combine 4 bf16 (uint2) from src/dst streams into 4 fp32.
static __device__ __forceinline__ fvec4 combine4(uint2 a, uint2 b)
{
    fvec4 r;
    r.x = (__uint_as_float(a.x << 16)         + __uint_as_float(b.x << 16))         * INV_SQRT_2F;
    r.y = (__uint_as_float(a.x & 0xffff0000u) + __uint_as_float(b.x & 0xffff0000u)) * INV_SQRT_2F;
    r.z = (__uint_as_float(a.y << 16)         + __uint_as_float(b.y << 16))         * INV_SQRT_2F;
    r.w = (__uint_as_float(a.y & 0xffff0000u) + __uint_as_float(b.y & 0xffff0000u)) * INV_SQRT_2F;
    return r;
}

// ---------------------------------------------------------------------------
// Prep: pack (src,dst) into one uint (nodes < 65536) -> 1 index load/thread.
// ---------------------------------------------------------------------------
__global__ void pack_sd(const int* __restrict__ src,
                        const int* __restrict__ dst,
                        unsigned int* __restrict__ sd, int edges)
{
    int i = blockIdx.x * blockDim.x + threadIdx.x;
    int stride = gridDim.x * blockDim.x;
    for (; i < edges; i += stride)
        sd[i] = ((unsigned int)src[i] << 16) | (unsigned int)dst[i];
}

// ---------------------------------------------------------------------------
// Kernel 1: per-node channel mix.  y[b,n,o,v] = sum_i W[o,i] * x[b,n,i,v]
// One block per (b,node). Threads 0..63 -> W_src rows, 64..127 -> W_dst rows.
// y stored as bf16, batch-interleaved per node (768 B contiguous per node).
// ---------------------------------------------------------------------------
__global__ void __launch_bounds__(128)
node_transform(const float* __restrict__ x,
               const float* __restrict__ W_src,
               const float* __restrict__ W_dst,
               unsigned short* __restrict__ y_src,
               unsigned short* __restrict__ y_dst,
               int nodes, int bn_total)
{
    __shared__ float xs[192];
    int bn = blockIdx.x;               // bn = b*nodes + n  (x is [b][n][192])
    if (bn >= bn_total) return;
    int b = bn / nodes;
    int n = bn - b * nodes;

    const float4* xp = (const float4*)(x + (size_t)bn * 192);
    int t = threadIdx.x;
    if (t < 48) ((float4*)xs)[t] = xp[t];   // 192 floats = 48 float4
    __syncthreads();

    int o = t & 63;
    const float*    W = (t < 64) ? W_src : W_dst;
    unsigned short* y = (t < 64) ? y_src : y_dst;

    const float4* Wrow = (const float4*)(W + o * 64);
    float a0 = 0.f, a1 = 0.f, a2 = 0.f;
#pragma unroll
    for (int i4 = 0; i4 < 16; ++i4) {
        float4 w = Wrow[i4];
        int i = i4 * 4;
        a0 = fmaf(w.x, xs[(i + 0) * 3 + 0], a0);
        a1 = fmaf(w.x, xs[(i + 0) * 3 + 1], a1);
        a2 = fmaf(w.x, xs[(i + 0) * 3 + 2], a2);
        a0 = fmaf(w.y, xs[(i + 1) * 3 + 0], a0);
        a1 = fmaf(w.y, xs[(i + 1) * 3 + 1], a1);
        a2 = fmaf(w.y, xs[(i + 1) * 3 + 2], a2);
        a0 = fmaf(w.z, xs[(i + 2) * 3 + 0], a0);
        a1 = fmaf(w.z, xs[(i + 2) * 3 + 1], a1);
        a2 = fmaf(w.z, xs[(i + 2) * 3 + 2], a2);
        a0 = fmaf(w.w, xs[(i + 3) * 3 + 0], a0);
        a1 = fmaf(w.w, xs[(i + 3) * 3 + 1], a1);
        a2 = fmaf(w.w, xs[(i + 3) * 3 + 2], a2);
    }
    unsigned short* yp = y + ((size_t)n * 2 + b) * 192 + o * 3;
    yp[0] = f2bf(a0);
    yp[1] = f2bf(a1);
    yp[2] = f2bf(a2);
}

// ---------------------------------------------------------------------------
// Kernel 2: edge gather (bf16) + add + scale -> fp32 NT stores, 2-edge unroll.
// Thread item = (e0, j) and (e1 = e0 + edges/2, j): 8 independent uint2 row
// loads in flight, 4 contiguous-per-instruction float4 NT stores.
// ---------------------------------------------------------------------------
__global__ void __launch_bounds__(256)
edge_combine2(const unsigned short* __restrict__ y_src,
              const unsigned short* __restrict__ y_dst,
              const unsigned int* __restrict__ sd,
              float* __restrict__ out,
              int edges)
{
    const int half   = edges >> 1;
    const int total  = half * 48;
    const int stride = gridDim.x * blockDim.x;
    const uint2* ys = (const uint2*)y_src;
    const uint2* yd = (const uint2*)y_dst;
    fvec4*       o4 = (fvec4*)out;

    for (int t = blockIdx.x * blockDim.x + threadIdx.x; t < total; t += stride) {
        int e0 = t / 48;
        int j  = t - e0 * 48;
        int e1 = e0 + half;

        unsigned int p0 = sd[e0];
        unsigned int p1 = sd[e1];
        size_t s0 = (size_t)(p0 >> 16)      * 96 + j;
        size_t d0 = (size_t)(p0 & 0xffffu)  * 96 + j;
        size_t s1 = (size_t)(p1 >> 16)      * 96 + j;
        size_t d1 = (size_t)(p1 & 0xffffu)  * 96 + j;

        // 8 independent gathers (edge0 b0/b1, edge1 b0/b1)
        uint2 a00 = ys[s0];
        uint2 b00 = yd[d0];
        uint2 a01 = ys[s0 + 48];
        uint2 b01 = yd[d0 + 48];
        uint2 a10 = ys[s1];
        uint2 b10 = yd[d1];
        uint2 a11 = ys[s1 + 48];
        uint2 b11 = yd[d1 + 48];

        __builtin_nontemporal_store(combine4(a00, b00), &o4[(size_t)e0 * 48 + j]);
        __builtin_nontemporal_store(combine4(a01, b01), &o4[((size_t)edges + e0) * 48 + j]);
        __builtin_nontemporal_store(combine4(a10, b10), &o4[(size_t)e1 * 48 + j]);
        __builtin_nontemporal_store(combine4(a11, b11), &o4[((size_t)edges + e1) * 48 + j]);
    }
}

// Tail kernel for odd edge counts: handles the single last edge.
__global__ void edge_combine_last(const unsigned short* __restrict__ y_src,
                                  const unsigned short* __restrict__ y_dst,
                                  const unsigned int* __restrict__ sd,
                                  float* __restrict__ out,
                                  int edges)
{
    int j = threadIdx.x;               // 48 threads
    int e = edges - 1;
    const uint2* ys = (const uint2*)y_src;
    const uint2* yd = (const uint2*)y_dst;
    fvec4*       o4 = (fvec4*)out;
    unsigned int p = sd[e];
    size_t s = (size_t)(p >> 16)     * 96 + j;
    size_t d = (size_t)(p & 0xffffu) * 96 + j;
    uint2 a0 = ys[s];
    uint2 b0 = yd[d];
    uint2 a1 = ys[s + 48];
    uint2 b1 = yd[d + 48];
    __builtin_nontemporal_store(combine4(a0, b0), &o4[(size_t)e * 48 + j]);
    __builtin_nontemporal_store(combine4(a1, b1), &o4[((size_t)edges + e) * 48 + j]);
}

// ---------------------------------------------------------------------------
// Unsorted R4 variant (fallback when nodes don't fit 16-bit packing).
// ---------------------------------------------------------------------------
__global__ void __launch_bounds__(256)
edge_combine(const unsigned short* __restrict__ y_src,
             const unsigned short* __restrict__ y_dst,
             const int* __restrict__ src,
             const int* __restrict__ dst,
             float* __restrict__ out,
             int edges)
{
    const int total  = edges * 48;
    const int stride = gridDim.x * blockDim.x;
    const uint2* ys = (const uint2*)y_src;
    const uint2* yd = (const uint2*)y_dst;
    fvec4*       o4 = (fvec4*)out;

    for (int t = blockIdx.x * blockDim.x + threadIdx.x; t < total; t += stride) {
        int e = t / 48;
        int j = t - e * 48;
        size_t sb = (size_t)src[e] * 96 + j;
        size_t db = (size_t)dst[e] * 96 + j;

        uint2 a0 = ys[sb];
        uint2 b0 = yd[db];
        uint2 a1 = ys[sb + 48];
        uint2 b1 = yd[db + 48];

        __builtin_nontemporal_store(combine4(a0, b0), &o4[(size_t)e * 48 + j]);
        __builtin_nontemporal_store(combine4(a1, b1), &o4[((size_t)edges + e) * 48 + j]);
    }
}

// ---------------------------------------------------------------------------
// Fallback (ws too small): fused per-edge matmul, fp32.
// ---------------------------------------------------------------------------
__global__ void __launch_bounds__(64)
edge_fused(const float* __restrict__ x,
           const float* __restrict__ W_src,
           const float* __restrict__ W_dst,
           const int* __restrict__ src,
           const int* __restrict__ dst,
           float* __restrict__ out,
           int edges, int nodes)
{
    __shared__ float xs[192];
    __shared__ float xd[192];
    int be = blockIdx.x;
    int b  = be / edges;
    int e  = be - b * edges;
    int s  = src[e];
    int d  = dst[e];
    const float* xps = x + ((size_t)b * nodes + s) * 192;
    const float* xpd = x + ((size_t)b * nodes + d) * 192;
    int t = threadIdx.x;
#pragma unroll
    for (int k = 0; k < 3; ++k) {
        xs[t + 64 * k] = xps[t + 64 * k];
        xd[t + 64 * k] = xpd[t + 64 * k];
    }
    __syncthreads();
    float a0 = 0.f, a1 = 0.f, a2 = 0.f;
#pragma unroll
    for (int i = 0; i < 64; ++i) {
        float ws = W_src[t * 64 + i];
        float wd = W_dst[t * 64 + i];
        a0 += ws * xs[i * 3 + 0] + wd * xd[i * 3 + 0];
        a1 += ws * xs[i * 3 + 1] + wd * xd[i * 3 + 1];
        a2 += ws * xs[i * 3 + 2] + wd * xd[i * 3 + 2];
    }
    float* op = out + ((size_t)b * edges + e) * 192 + t * 3;
    op[0] = a0 * INV_SQRT_2F;
    op[1] = a1 * INV_SQRT_2F;
    op[2] = a2 * INV_SQRT_2F;
}

extern "C" void kernel_launch(void* const* d_in, const int* in_sizes, int n_in,
                              void* d_out, int out_size, void* d_ws, size_t ws_size,
                              hipStream_t stream)
{
    const float* x     = (const float*)d_in[0];
    const float* W_src = (const float*)d_in[1];
    const float* W_dst = (const float*)d_in[2];
    const int*   src   = (const int*)d_in[3];
    const int*   dst   = (const int*)d_in[4];
    float*       out   = (float*)d_out;

    const int batch = 2;
    const int edges = in_sizes[3];
    const int nodes = in_sizes[0] / (batch * 192);   // 192 = dim_in * 3

    const size_t y_elems = (size_t)batch * nodes * 192;          // per array
    const size_t y_bytes = ((y_elems * 2 + 255) / 256) * 256;    // bf16, aligned
    const size_t sd_bytes = (((size_t)edges * 4 + 255) / 256) * 256;
    const size_t needed_packed = 2 * y_bytes + sd_bytes;
    const size_t needed_plain  = 2 * y_bytes;

    char* wsb = (char*)d_ws;
    const int bn_total = batch * nodes;

    if (ws_size >= needed_packed && nodes <= 65535) {
        unsigned short* y_src = (unsigned short*)wsb;
        unsigned short* y_dst = (unsigned short*)(wsb + y_bytes);
        unsigned int*   sd    = (unsigned int*)(wsb + 2 * y_bytes);

        node_transform<<<bn_total, 128, 0, stream>>>(x, W_src, W_dst,
                                                     y_src, y_dst, nodes, bn_total);
        int egrid = (edges + 255) / 256; if (egrid > 1024) egrid = 1024;
        pack_sd<<<egrid, 256, 0, stream>>>(src, dst, sd, edges);
        edge_combine2<<<2048, 256, 0, stream>>>(y_src, y_dst, sd, out, edges);
        if (edges & 1)
            edge_combine_last<<<1, 48, 0, stream>>>(y_src, y_dst, sd, out, edges);
    } else if (ws_size >= needed_plain) {
        unsigned short* y_src = (unsigned short*)wsb;
        unsigned short* y_dst = (unsigned short*)(wsb + y_bytes);
        node_transform<<<bn_total, 128, 0, stream>>>(x, W_src, W_dst,
                                                     y_src, y_dst, nodes, bn_total);
        edge_combine<<<2048, 256, 0, stream>>>(y_src, y_dst, src, dst, out, edges);
    } else {
        edge_fused<<<batch * edges, 64, 0, stream>>>(x, W_src, W_dst,
                                                     src, dst, out, edges, nodes);
    }
}

// Round 8
// 210.620 us; speedup vs baseline: 1.2432x; 1.0034x over previous
//
#include <hip/hip_runtime.h>

#define INV_SQRT_2F 0.70710678118654752440f

typedef float fvec4 __attribute__((ext_vector_type(4)));

// fp32 -> bf16 bits, round-to-nearest-even (inputs are normal floats here).
static __device__ __forceinline__ unsigned short f2bf(float f)
{
    unsigned int u = __float_as_uint(f);
    u += 0x7fffu + ((u >> 16) & 1u);
    return (unsigned short)(u >> 16);
}

// Combine 4 bf16 (uint2) from src/dst streams into 4 fp32.
static __device__ __forceinline__ fvec4 combine4(uint2 a, uint2 b)
{
    fvec4 r;
    r.x = (__uint_as_float(a.x << 16)         + __uint_as_float(b.x << 16))         * INV_SQRT_2F;
    r.y = (__uint_as_float(a.x & 0xffff0000u) + __uint_as_float(b.x & 0xffff0000u)) * INV_SQRT_2F;
    r.z = (__uint_as_float(a.y << 16)         + __uint_as_float(b.y << 16))         * INV_SQRT_2F;
    r.w = (__uint_as_float(a.y & 0xffff0000u) + __uint_as_float(b.y & 0xffff0000u)) * INV_SQRT_2F;
    return r;
}

// 8-byte lane exchange with lane^1.
static __device__ __forceinline__ uint2 xchg1(uint2 v)
{
    uint2 r;
    r.x = __shfl_xor((unsigned int)v.x, 1);
    r.y = __shfl_xor((unsigned int)v.y, 1);
    return r;
}

// ---------------------------------------------------------------------------
// Prep: pack (src,dst) into one uint (nodes < 65536) -> 1 index load/thread.
// ---------------------------------------------------------------------------
__global__ void pack_sd(const int* __restrict__ src,
                        const int* __restrict__ dst,
                        unsigned int* __restrict__ sd, int edges)
{
    int i = blockIdx.x * blockDim.x + threadIdx.x;
    int stride = gridDim.x * blockDim.x;
    for (; i < edges; i += stride)
        sd[i] = ((unsigned int)src[i] << 16) | (unsigned int)dst[i];
}

// ---------------------------------------------------------------------------
// Kernel 1: per-node channel mix.  y[b,n,o,v] = sum_i W[o,i] * x[b,n,i,v]
// One block per (b,node). Threads 0..63 -> W_src rows, 64..127 -> W_dst rows.
// y stored as bf16, batch-interleaved per node (768 B contiguous per node).
// ---------------------------------------------------------------------------
__global__ void __launch_bounds__(128)
node_transform(const float* __restrict__ x,
               const float* __restrict__ W_src,
               const float* __restrict__ W_dst,
               unsigned short* __restrict__ y_src,
               unsigned short* __restrict__ y_dst,
               int nodes, int bn_total)
{
    __shared__ float xs[192];
    int bn = blockIdx.x;               // bn = b*nodes + n  (x is [b][n][192])
    if (bn >= bn_total) return;
    int b = bn / nodes;
    int n = bn - b * nodes;

    const float4* xp = (const float4*)(x + (size_t)bn * 192);
    int t = threadIdx.x;
    if (t < 48) ((float4*)xs)[t] = xp[t];   // 192 floats = 48 float4
    __syncthreads();

    int o = t & 63;
    const float*    W = (t < 64) ? W_src : W_dst;
    unsigned short* y = (t < 64) ? y_src : y_dst;

    const float4* Wrow = (const float4*)(W + o * 64);
    float a0 = 0.f, a1 = 0.f, a2 = 0.f;
#pragma unroll
    for (int i4 = 0; i4 < 16; ++i4) {
        float4 w = Wrow[i4];
        int i = i4 * 4;
        a0 = fmaf(w.x, xs[(i + 0) * 3 + 0], a0);
        a1 = fmaf(w.x, xs[(i + 0) * 3 + 1], a1);
        a2 = fmaf(w.x, xs[(i + 0) * 3 + 2], a2);
        a0 = fmaf(w.y, xs[(i + 1) * 3 + 0], a0);
        a1 = fmaf(w.y, xs[(i + 1) * 3 + 1], a1);
        a2 = fmaf(w.y, xs[(i + 1) * 3 + 2], a2);
        a0 = fmaf(w.z, xs[(i + 2) * 3 + 0], a0);
        a1 = fmaf(w.z, xs[(i + 2) * 3 + 1], a1);
        a2 = fmaf(w.z, xs[(i + 2) * 3 + 2], a2);
        a0 = fmaf(w.w, xs[(i + 3) * 3 + 0], a0);
        a1 = fmaf(w.w, xs[(i + 3) * 3 + 1], a1);
        a2 = fmaf(w.w, xs[(i + 3) * 3 + 2], a2);
    }
    unsigned short* yp = y + ((size_t)n * 2 + b) * 192 + o * 3;
    yp[0] = f2bf(a0);
    yp[1] = f2bf(a1);
    yp[2] = f2bf(a2);
}

// ---------------------------------------------------------------------------
// Kernel 2: paired-gather edge combine.  Item = (g, j): 4 edges
// {2g, 2g+1, 2Q+2g, 2Q+2g+1} at out-quad j.  Lane pairs (j even, j+1) share
// an edge: even lane loads 16 B of the SRC row, odd lane 16 B of the DST row
// (both batches), one 8 B shfl_xor exchange delivers both quads to both lanes.
// Stores stay per-instruction lane-contiguous (R5 lesson), NT (R3 lesson).
// Node row in uint4 units: 48 per node (24 per batch).
// ---------------------------------------------------------------------------
__global__ void __launch_bounds__(256)
edge_combine_p(const unsigned short* __restrict__ y_src,
               const unsigned short* __restrict__ y_dst,
               const unsigned int* __restrict__ sd,
               float* __restrict__ out,
               int edges)
{
    const int Q = edges >> 2;                // quads of edges; tail handled separately
    const int total = Q * 48;                // even (48 even) -> pair-safe guard
    const int stride = gridDim.x * blockDim.x;
    const uint4* ys4 = (const uint4*)y_src;
    const uint4* yd4 = (const uint4*)y_dst;
    fvec4*       o4  = (fvec4*)out;

    for (int t = blockIdx.x * blockDim.x + threadIdx.x; t < total; t += stride) {
        int g  = t / 48;
        int j  = t - g * 48;                 // parity(j) == parity(lane)
        int par = j & 1;
        int jj  = j >> 1;                    // uint4 index within batch-0 half of row

        uint2 p01 = *(const uint2*)&sd[2 * g];           // edges 2g, 2g+1
        uint2 p23 = *(const uint2*)&sd[2 * Q + 2 * g];   // edges 2Q+2g, 2Q+2g+1
        unsigned int pk[4] = { p01.x, p01.y, p23.x, p23.y };
        int ek[4] = { 2 * g, 2 * g + 1, 2 * Q + 2 * g, 2 * Q + 2 * g + 1 };

        const uint4* base = par ? yd4 : ys4;

#pragma unroll
        for (int k = 0; k < 4; ++k) {
            unsigned int row = par ? (pk[k] & 0xffffu) : (pk[k] >> 16);
            const uint4* rp = base + (size_t)row * 48 + jj;
            uint4 v0 = rp[0];                // batch 0: quads {J, J+1}
            uint4 v1 = rp[24];               // batch 1

            // batch 0: keep own quad, exchange the other with lane^1
            uint2 kept0 = par ? make_uint2(v0.z, v0.w) : make_uint2(v0.x, v0.y);
            uint2 send0 = par ? make_uint2(v0.x, v0.y) : make_uint2(v0.z, v0.w);
            uint2 recv0 = xchg1(send0);
            __builtin_nontemporal_store(combine4(kept0, recv0),
                                        &o4[(size_t)ek[k] * 48 + j]);

            // batch 1
            uint2 kept1 = par ? make_uint2(v1.z, v1.w) : make_uint2(v1.x, v1.y);
            uint2 send1 = par ? make_uint2(v1.x, v1.y) : make_uint2(v1.z, v1.w);
            uint2 recv1 = xchg1(send1);
            __builtin_nontemporal_store(combine4(kept1, recv1),
                                        &o4[((size_t)edges + ek[k]) * 48 + j]);
        }
    }
}

// Tail kernel: edges in [e_begin, edges), scalar per-quad (R4-style).
__global__ void edge_combine_tail(const unsigned short* __restrict__ y_src,
                                  const unsigned short* __restrict__ y_dst,
                                  const unsigned int* __restrict__ sd,
                                  float* __restrict__ out,
                                  int edges, int e_begin)
{
    int idx = blockIdx.x * blockDim.x + threadIdx.x;
    int nt = (edges - e_begin) * 48;
    if (idx >= nt) return;
    int e = e_begin + idx / 48;
    int j = idx - (idx / 48) * 48;
    const uint2* ys = (const uint2*)y_src;
    const uint2* yd = (const uint2*)y_dst;
    fvec4*       o4 = (fvec4*)out;
    unsigned int p = sd[e];
    size_t s = (size_t)(p >> 16)     * 96 + j;
    size_t d = (size_t)(p & 0xffffu) * 96 + j;
    uint2 a0 = ys[s];
    uint2 b0 = yd[d];
    uint2 a1 = ys[s + 48];
    uint2 b1 = yd[d + 48];
    __builtin_nontemporal_store(combine4(a0, b0), &o4[(size_t)e * 48 + j]);
    __builtin_nontemporal_store(combine4(a1, b1), &o4[((size_t)edges + e) * 48 + j]);
}

// ---------------------------------------------------------------------------
// Unsorted R4 variant (fallback when nodes don't fit 16-bit packing).
// ---------------------------------------------------------------------------
__global__ void __launch_bounds__(256)
edge_combine(const unsigned short* __restrict__ y_src,
             const unsigned short* __restrict__ y_dst,
             const int* __restrict__ src,
             const int* __restrict__ dst,
             float* __restrict__ out,
             int edges)
{
    const int total  = edges * 48;
    const int stride = gridDim.x * blockDim.x;
    const uint2* ys = (const uint2*)y_src;
    const uint2* yd = (const uint2*)y_dst;
    fvec4*       o4 = (fvec4*)out;

    for (int t = blockIdx.x * blockDim.x + threadIdx.x; t < total; t += stride) {
        int e = t / 48;
        int j = t - e * 48;
        size_t sb = (size_t)src[e] * 96 + j;
        size_t db = (size_t)dst[e] * 96 + j;

        uint2 a0 = ys[sb];
        uint2 b0 = yd[db];
        uint2 a1 = ys[sb + 48];
        uint2 b1 = yd[db + 48];

        __builtin_nontemporal_store(combine4(a0, b0), &o4[(size_t)e * 48 + j]);
        __builtin_nontemporal_store(combine4(a1, b1), &o4[((size_t)edges + e) * 48 + j]);
    }
}

// ---------------------------------------------------------------------------
// Fallback (ws too small): fused per-edge matmul, fp32.
// ---------------------------------------------------------------------------
__global__ void __launch_bounds__(64)
edge_fused(const float* __restrict__ x,
           const float* __restrict__ W_src,
           const float* __restrict__ W_dst,
           const int* __restrict__ src,
           const int* __restrict__ dst,
           float* __restrict__ out,
           int edges, int nodes)
{
    __shared__ float xs[192];
    __shared__ float xd[192];
    int be = blockIdx.x;
    int b  = be / edges;
    int e  = be - b * edges;
    int s  = src[e];
    int d  = dst[e];
    const float* xps = x + ((size_t)b * nodes + s) * 192;
    const float* xpd = x + ((size_t)b * nodes + d) * 192;
    int t = threadIdx.x;
#pragma unroll
    for (int k = 0; k < 3; ++k) {
        xs[t + 64 * k] = xps[t + 64 * k];
        xd[t + 64 * k] = xpd[t + 64 * k];
    }
    __syncthreads();
    float a0 = 0.f, a1 = 0.f, a2 = 0.f;
#pragma unroll
    for (int i = 0; i < 64; ++i) {
        float ws = W_src[t * 64 + i];
        float wd = W_dst[t * 64 + i];
        a0 += ws * xs[i * 3 + 0] + wd * xd[i * 3 + 0];
        a1 += ws * xs[i * 3 + 1] + wd * xd[i * 3 + 1];
        a2 += ws * xs[i * 3 + 2] + wd * xd[i * 3 + 2];
    }
    float* op = out + ((size_t)b * edges + e) * 192 + t * 3;
    op[0] = a0 * INV_SQRT_2F;
    op[1] = a1 * INV_SQRT_2F;
    op[2] = a2 * INV_SQRT_2F;
}

extern "C" void kernel_launch(void* const* d_in, const int* in_sizes, int n_in,
                              void* d_out, int out_size, void* d_ws, size_t ws_size,
                              hipStream_t stream)
{
    const float* x     = (const float*)d_in[0];
    const float* W_src = (const float*)d_in[1];
    const float* W_dst = (const float*)d_in[2];
    const int*   src   = (const int*)d_in[3];
    const int*   dst   = (const int*)d_in[4];
    float*       out   = (float*)d_out;

    const int batch = 2;
    const int edges = in_sizes[3];
    const int nodes = in_sizes[0] / (batch * 192);   // 192 = dim_in * 3

    const size_t y_elems = (size_t)batch * nodes * 192;          // per array
    const size_t y_bytes = ((y_elems * 2 + 255) / 256) * 256;    // bf16, aligned
    const size_t sd_bytes = (((size_t)edges * 4 + 255) / 256) * 256;
    const size_t needed_packed = 2 * y_bytes + sd_bytes;
    const size_t needed_plain  = 2 * y_bytes;

    char* wsb = (char*)d_ws;
    const int bn_total = batch * nodes;

    if (ws_size >= needed_packed && nodes <= 65535 && edges >= 4) {
        unsigned short* y_src = (unsigned short*)wsb;
        unsigned short* y_dst = (unsigned short*)(wsb + y_bytes);
        unsigned int*   sd    = (unsigned int*)(wsb + 2 * y_bytes);

        node_transform<<<bn_total, 128, 0, stream>>>(x, W_src, W_dst,
                                                     y_src, y_dst, nodes, bn_total);
        int egrid = (edges + 255) / 256; if (egrid > 1024) egrid = 1024;
        pack_sd<<<egrid, 256, 0, stream>>>(src, dst, sd, edges);
        edge_combine_p<<<2048, 256, 0, stream>>>(y_src, y_dst, sd, out, edges);
        int tail = edges & 3;
        if (tail)
            edge_combine_tail<<<1, 256, 0, stream>>>(y_src, y_dst, sd, out,
                                                     edges, edges - tail);
    } else if (ws_size >= needed_plain) {
        unsigned short* y_src = (unsigned short*)wsb;
        unsigned short* y_dst = (unsigned short*)(wsb + y_bytes);
        node_transform<<<bn_total, 128, 0, stream>>>(x, W_src, W_dst,
                                                     y_src, y_dst, nodes, bn_total);
        edge_combine<<<2048, 256, 0, stream>>>(y_src, y_dst, src, dst, out, edges);
    } else {
        edge_fused<<<batch * edges, 64, 0, stream>>>(x, W_src, W_dst,
                                                     src, dst, out, edges, nodes);
    }
}